// Round 1
// baseline (415.610 us; speedup 1.0000x reference)
//
#include <hip/hip_runtime.h>
#include <cmath>

#define THREADS 256

__device__ __forceinline__ int lower_bound_i(const int* __restrict__ arr, int n, int val) {
    int lo = 0, hi = n;
    while (lo < hi) {
        int mid = (lo + hi) >> 1;
        if (arr[mid] < val) lo = mid + 1; else hi = mid;
    }
    return lo;
}

// One block per graph. batch is sorted, so each graph's nodes are a contiguous
// row range [lo, hi) found by binary search. Computes
//   x[g][c] = (seg_sum[g][c]/cnt)*log(cnt) + vn[g][c]
__global__ void pool_kernel(const float* __restrict__ feat, const float* __restrict__ vn,
                            const int* __restrict__ batch, float* __restrict__ x,
                            int N, int D) {
    int g = blockIdx.x;
    __shared__ int s_range[2];
    if (threadIdx.x < 2) s_range[threadIdx.x] = lower_bound_i(batch, N, g + (int)threadIdx.x);
    __syncthreads();
    int lo = s_range[0], hi = s_range[1];
    int cnt = hi - lo;
    float scale = (cnt > 0) ? (logf((float)cnt) / (float)cnt) : 0.f;

    float acc[4] = {0.f, 0.f, 0.f, 0.f};
    int t = threadIdx.x;
    for (int r = lo; r < hi; ++r) {
        const float* __restrict__ row = feat + (size_t)r * D;
#pragma unroll
        for (int j = 0; j < 4; ++j) {
            int c = t + j * THREADS;
            if (c < D) acc[j] += row[c];
        }
    }
#pragma unroll
    for (int j = 0; j < 4; ++j) {
        int c = t + j * THREADS;
        if (c < D) x[(size_t)g * D + c] = acc[j] * scale + vn[(size_t)g * D + c];
    }
}

// C[M,Nn] = A[M,K] @ W[K,Nn] + bias; optional relu; optional residual add.
// BM=BN=64, BK=16, 256 threads, 4x4 per thread.
template <bool RELU, bool ADD_RES>
__global__ void gemm_kernel(const float* __restrict__ A, const float* __restrict__ W,
                            const float* __restrict__ bias, const float* __restrict__ res,
                            float* __restrict__ out, int M, int Nn, int K) {
    __shared__ float As[64][17];
    __shared__ float Bs[16][65];

    int tid = threadIdx.x;
    int tx = tid & 15;   // 0..15  (col group)
    int ty = tid >> 4;   // 0..15  (row group)
    int bm = blockIdx.y; // tile row
    int bn = blockIdx.x; // tile col

    float acc[4][4] = {};

    int nk = K / 16;
    for (int kt = 0; kt < nk; ++kt) {
        // A tile: 64 rows x 16 cols, one float4 per thread
        {
            int row = tid >> 2;        // 0..63
            int col = (tid & 3) * 4;   // 0,4,8,12
            const float4 av = *(const float4*)(A + (size_t)(bm * 64 + row) * K + kt * 16 + col);
            As[row][col + 0] = av.x;
            As[row][col + 1] = av.y;
            As[row][col + 2] = av.z;
            As[row][col + 3] = av.w;
        }
        // B tile: 16 rows x 64 cols, one float4 per thread
        {
            int row = tid >> 4;        // 0..15
            int col = (tid & 15) * 4;  // 0..60
            const float4 bv = *(const float4*)(W + (size_t)(kt * 16 + row) * Nn + bn * 64 + col);
            Bs[row][col + 0] = bv.x;
            Bs[row][col + 1] = bv.y;
            Bs[row][col + 2] = bv.z;
            Bs[row][col + 3] = bv.w;
        }
        __syncthreads();

#pragma unroll
        for (int k = 0; k < 16; ++k) {
            float a[4], b[4];
#pragma unroll
            for (int i = 0; i < 4; ++i) a[i] = As[ty * 4 + i][k];
#pragma unroll
            for (int j = 0; j < 4; ++j) b[j] = Bs[k][tx * 4 + j];
#pragma unroll
            for (int i = 0; i < 4; ++i)
#pragma unroll
                for (int j = 0; j < 4; ++j) acc[i][j] += a[i] * b[j];
        }
        __syncthreads();
    }

#pragma unroll
    for (int i = 0; i < 4; ++i) {
        int row = bm * 64 + ty * 4 + i;
#pragma unroll
        for (int j = 0; j < 4; ++j) {
            int col = bn * 64 + tx * 4 + j;
            float v = acc[i][j] + bias[col];
            if (RELU) v = fmaxf(v, 0.f);
            if (ADD_RES) v += res[(size_t)row * Nn + col];
            out[(size_t)row * Nn + col] = v;
        }
    }
}

// feat_out[i][:] = feat[i][:] + y[batch[i]][:]   (float4-vectorized grid-stride)
__global__ void node_add_kernel(const float* __restrict__ feat, const float* __restrict__ y,
                                const int* __restrict__ batch, float* __restrict__ out,
                                int total4, int D4) {
    for (int i = blockIdx.x * blockDim.x + threadIdx.x; i < total4;
         i += gridDim.x * blockDim.x) {
        int node = i / D4;
        int c = i - node * D4;
        int b = batch[node];
        float4 f = ((const float4*)feat)[i];
        float4 v = ((const float4*)y)[(size_t)b * D4 + c];
        f.x += v.x; f.y += v.y; f.z += v.z; f.w += v.w;
        ((float4*)out)[i] = f;
    }
}

extern "C" void kernel_launch(void* const* d_in, const int* in_sizes, int n_in,
                              void* d_out, int out_size, void* d_ws, size_t ws_size,
                              hipStream_t stream) {
    const float* feat  = (const float*)d_in[0];
    const float* vn    = (const float*)d_in[1];
    const float* edge  = (const float*)d_in[2];
    const int*   batch = (const int*)d_in[3];
    // d_in[4] = num_graphs (derived from sizes instead)
    const float* fcW   = (const float*)d_in[5];
    const float* fcb   = (const float*)d_in[6];
    const float* pW    = (const float*)d_in[7];
    const float* pb    = (const float*)d_in[8];

    const int D = in_sizes[6];            // 768
    const int N = in_sizes[0] / D;        // 100000
    const int B = in_sizes[1] / D;        // 1024
    const int edge_elems = in_sizes[2];   // B*DE

    float* out_feat = (float*)d_out;
    float* out_vn   = out_feat + (size_t)N * D;
    float* out_edge = out_vn + (size_t)B * D;

    float* x = (float*)d_ws;              // [B, D]
    float* y = x + (size_t)B * D;         // [B, D]

    // 1) pool + vn add -> x
    pool_kernel<<<B, THREADS, 0, stream>>>(feat, vn, batch, x, N, D);

    // 2) vn_new = vn + relu(x @ fcW + fcb)   -> out_vn (also feeds GEMM2)
    dim3 gdim(D / 64, B / 64);
    gemm_kernel<true, true><<<gdim, THREADS, 0, stream>>>(x, fcW, fcb, vn, out_vn, B, D, D);

    // 3) y = vn_new @ pW + pb
    gemm_kernel<false, false><<<gdim, THREADS, 0, stream>>>(out_vn, pW, pb, nullptr, y, B, D, D);

    // 4) feat_out = feat + y[batch]
    const int D4 = D / 4;
    const int total4 = N * D4;
    node_add_kernel<<<2048, THREADS, 0, stream>>>(feat, y, batch, out_feat, total4, D4);

    // 5) edge passthrough
    hipMemcpyAsync(out_edge, edge, (size_t)edge_elems * sizeof(float),
                   hipMemcpyDeviceToDevice, stream);
}

// Round 2
// 301.488 us; speedup vs baseline: 1.3785x; 1.3785x over previous
//
#include <hip/hip_runtime.h>
#include <cmath>

#define THREADS 256
#define PCOLS 192   // 768 floats / 4 = 192 float4 columns

__device__ __forceinline__ int lower_bound_i(const int* __restrict__ arr, int n, int val) {
    int lo = 0, hi = n;
    while (lo < hi) {
        int mid = (lo + hi) >> 1;
        if (arr[mid] < val) lo = mid + 1; else hi = mid;
    }
    return lo;
}

__device__ __forceinline__ float4 f4add(float4 a, float4 b) {
    a.x += b.x; a.y += b.y; a.z += b.z; a.w += b.w; return a;
}
__device__ __forceinline__ float4 f4fma(float4 a, float s, float4 b) {
    b.x += a.x * s; b.y += a.y * s; b.z += a.z * s; b.w += a.w * s; return b;
}

// One block (192 threads) per graph; thread t owns float4 column t.
// 8-row unroll with 8 independent accumulators to keep ~128B/thread in flight.
//   x[g][c] = seg_sum[g][c] * (log(cnt)/cnt) + vn[g][c]
__global__ void pool_kernel(const float4* __restrict__ feat4, const float4* __restrict__ vn4,
                            const int* __restrict__ batch, float4* __restrict__ x4,
                            int N, int D4) {
    int g = blockIdx.x;
    __shared__ int s_range[2];
    if (threadIdx.x < 2) s_range[threadIdx.x] = lower_bound_i(batch, N, g + (int)threadIdx.x);
    __syncthreads();
    int lo = s_range[0], hi = s_range[1];
    int cnt = hi - lo;
    float scale = (cnt > 0) ? (logf((float)cnt) / (float)cnt) : 0.f;

    int t = threadIdx.x;
    float4 a0 = {0,0,0,0}, a1 = {0,0,0,0}, a2 = {0,0,0,0}, a3 = {0,0,0,0};
    float4 a4 = {0,0,0,0}, a5 = {0,0,0,0}, a6 = {0,0,0,0}, a7 = {0,0,0,0};

    const float4* __restrict__ p = feat4 + (size_t)lo * D4 + t;
    int r = lo;
    for (; r + 8 <= hi; r += 8) {
        float4 v0 = p[0 * (size_t)D4];
        float4 v1 = p[1 * (size_t)D4];
        float4 v2 = p[2 * (size_t)D4];
        float4 v3 = p[3 * (size_t)D4];
        float4 v4 = p[4 * (size_t)D4];
        float4 v5 = p[5 * (size_t)D4];
        float4 v6 = p[6 * (size_t)D4];
        float4 v7 = p[7 * (size_t)D4];
        a0 = f4add(a0, v0); a1 = f4add(a1, v1); a2 = f4add(a2, v2); a3 = f4add(a3, v3);
        a4 = f4add(a4, v4); a5 = f4add(a5, v5); a6 = f4add(a6, v6); a7 = f4add(a7, v7);
        p += 8 * (size_t)D4;
    }
    for (; r < hi; ++r) {
        a0 = f4add(a0, p[0]);
        p += D4;
    }
    float4 s = f4add(f4add(f4add(a0, a1), f4add(a2, a3)), f4add(f4add(a4, a5), f4add(a6, a7)));
    float4 vnv = vn4[(size_t)g * D4 + t];
    x4[(size_t)g * D4 + t] = f4fma(s, scale, vnv);
}

// C[M,Nn] = A[M,K] @ W[K,Nn] + bias; optional relu; optional residual add.
// BM=BN=64, BK=16, 256 threads, 4x4 per thread.
template <bool RELU, bool ADD_RES>
__global__ void gemm_kernel(const float* __restrict__ A, const float* __restrict__ W,
                            const float* __restrict__ bias, const float* __restrict__ res,
                            float* __restrict__ out, int M, int Nn, int K) {
    __shared__ float As[64][17];
    __shared__ float Bs[16][65];

    int tid = threadIdx.x;
    int tx = tid & 15;
    int ty = tid >> 4;
    int bm = blockIdx.y;
    int bn = blockIdx.x;

    float acc[4][4] = {};

    int nk = K / 16;
    for (int kt = 0; kt < nk; ++kt) {
        {
            int row = tid >> 2;
            int col = (tid & 3) * 4;
            const float4 av = *(const float4*)(A + (size_t)(bm * 64 + row) * K + kt * 16 + col);
            As[row][col + 0] = av.x;
            As[row][col + 1] = av.y;
            As[row][col + 2] = av.z;
            As[row][col + 3] = av.w;
        }
        {
            int row = tid >> 4;
            int col = (tid & 15) * 4;
            const float4 bv = *(const float4*)(W + (size_t)(kt * 16 + row) * Nn + bn * 64 + col);
            Bs[row][col + 0] = bv.x;
            Bs[row][col + 1] = bv.y;
            Bs[row][col + 2] = bv.z;
            Bs[row][col + 3] = bv.w;
        }
        __syncthreads();

#pragma unroll
        for (int k = 0; k < 16; ++k) {
            float a[4], b[4];
#pragma unroll
            for (int i = 0; i < 4; ++i) a[i] = As[ty * 4 + i][k];
#pragma unroll
            for (int j = 0; j < 4; ++j) b[j] = Bs[k][tx * 4 + j];
#pragma unroll
            for (int i = 0; i < 4; ++i)
#pragma unroll
                for (int j = 0; j < 4; ++j) acc[i][j] += a[i] * b[j];
        }
        __syncthreads();
    }

#pragma unroll
    for (int i = 0; i < 4; ++i) {
        int row = bm * 64 + ty * 4 + i;
#pragma unroll
        for (int j = 0; j < 4; ++j) {
            int col = bn * 64 + tx * 4 + j;
            float v = acc[i][j] + bias[col];
            if (RELU) v = fmaxf(v, 0.f);
            if (ADD_RES) v += res[(size_t)row * Nn + col];
            out[(size_t)row * Nn + col] = v;
        }
    }
}

// feat_out[node][:] = feat[node][:] + y[batch[node]][:]
// block = (192 cols, 2 nodes); no per-element integer division.
__global__ void node_add_kernel(const float4* __restrict__ feat4, const float4* __restrict__ y4,
                                const int* __restrict__ batch, float4* __restrict__ out4,
                                int N, int D4) {
    int node = blockIdx.x * blockDim.y + threadIdx.y;
    if (node >= N) return;
    int t = threadIdx.x;
    int b = batch[node];
    float4 f = feat4[(size_t)node * D4 + t];
    float4 v = y4[(size_t)b * D4 + t];
    f.x += v.x; f.y += v.y; f.z += v.z; f.w += v.w;
    out4[(size_t)node * D4 + t] = f;
}

extern "C" void kernel_launch(void* const* d_in, const int* in_sizes, int n_in,
                              void* d_out, int out_size, void* d_ws, size_t ws_size,
                              hipStream_t stream) {
    const float* feat  = (const float*)d_in[0];
    const float* vn    = (const float*)d_in[1];
    const float* edge  = (const float*)d_in[2];
    const int*   batch = (const int*)d_in[3];
    const float* fcW   = (const float*)d_in[5];
    const float* fcb   = (const float*)d_in[6];
    const float* pW    = (const float*)d_in[7];
    const float* pb    = (const float*)d_in[8];

    const int D = in_sizes[6];            // 768
    const int N = in_sizes[0] / D;        // 100000
    const int B = in_sizes[1] / D;        // 1024
    const int edge_elems = in_sizes[2];   // B*DE
    const int D4 = D / 4;                 // 192

    float* out_feat = (float*)d_out;
    float* out_vn   = out_feat + (size_t)N * D;
    float* out_edge = out_vn + (size_t)B * D;

    float* x = (float*)d_ws;              // [B, D]
    float* y = x + (size_t)B * D;         // [B, D]

    // 1) pool + vn add -> x
    pool_kernel<<<B, PCOLS, 0, stream>>>((const float4*)feat, (const float4*)vn,
                                         batch, (float4*)x, N, D4);

    // 2) vn_new = vn + relu(x @ fcW + fcb) -> out_vn
    dim3 gdim(D / 64, B / 64);
    gemm_kernel<true, true><<<gdim, THREADS, 0, stream>>>(x, fcW, fcb, vn, out_vn, B, D, D);

    // 3) y = vn_new @ pW + pb
    gemm_kernel<false, false><<<gdim, THREADS, 0, stream>>>(out_vn, pW, pb, nullptr, y, B, D, D);

    // 4) feat_out = feat + y[batch]
    dim3 nblk(192, 2);
    node_add_kernel<<<(N + 1) / 2, nblk, 0, stream>>>((const float4*)feat, (const float4*)y,
                                                      batch, (float4*)out_feat, N, D4);

    // 5) edge passthrough
    hipMemcpyAsync(out_edge, edge, (size_t)edge_elems * sizeof(float),
                   hipMemcpyDeviceToDevice, stream);
}

// Round 3
// 222.445 us; speedup vs baseline: 1.8684x; 1.3553x over previous
//
#include <hip/hip_runtime.h>
#include <cmath>

#define THREADS 256
#define PCOLS 192   // 768 floats / 4 = 192 float4 columns

typedef __attribute__((ext_vector_type(8))) short bf16x8;
typedef __attribute__((ext_vector_type(4))) float f32x4;

__device__ __forceinline__ short f2bf(float f) {
    // truncation: error unbiased-enough over +/- random dot products; 1 VALU op
    return (short)(__builtin_bit_cast(unsigned, f) >> 16);
}

typedef const __attribute__((address_space(1))) unsigned int* gas1_t;
typedef __attribute__((address_space(3))) unsigned int* las3_t;
__device__ __forceinline__ void gload16(const float* g, float* l) {
    __builtin_amdgcn_global_load_lds((gas1_t)g, (las3_t)l, 16, 0, 0);
}

__device__ __forceinline__ int lower_bound_i(const int* __restrict__ arr, int n, int val) {
    int lo = 0, hi = n;
    while (lo < hi) {
        int mid = (lo + hi) >> 1;
        if (arr[mid] < val) lo = mid + 1; else hi = mid;
    }
    return lo;
}

__device__ __forceinline__ float4 f4add(float4 a, float4 b) {
    a.x += b.x; a.y += b.y; a.z += b.z; a.w += b.w; return a;
}
__device__ __forceinline__ float4 f4fma(float4 a, float s, float4 b) {
    b.x += a.x * s; b.y += a.y * s; b.z += a.z * s; b.w += a.w * s; return b;
}

// ---------------- pool: x[g] = seg_mean(feat) * log(cnt) + vn[g] ----------------
__global__ void pool_kernel(const float4* __restrict__ feat4, const float4* __restrict__ vn4,
                            const int* __restrict__ batch, float4* __restrict__ x4,
                            int N, int D4) {
    int g = blockIdx.x;
    __shared__ int s_range[2];
    if (threadIdx.x < 2) s_range[threadIdx.x] = lower_bound_i(batch, N, g + (int)threadIdx.x);
    __syncthreads();
    int lo = s_range[0], hi = s_range[1];
    int cnt = hi - lo;
    float scale = (cnt > 0) ? (logf((float)cnt) / (float)cnt) : 0.f;

    int t = threadIdx.x;
    float4 a0 = {0,0,0,0}, a1 = {0,0,0,0}, a2 = {0,0,0,0}, a3 = {0,0,0,0};
    float4 a4 = {0,0,0,0}, a5 = {0,0,0,0}, a6 = {0,0,0,0}, a7 = {0,0,0,0};

    const float4* __restrict__ p = feat4 + (size_t)lo * D4 + t;
    int r = lo;
    for (; r + 8 <= hi; r += 8) {
        float4 v0 = p[0 * (size_t)D4];
        float4 v1 = p[1 * (size_t)D4];
        float4 v2 = p[2 * (size_t)D4];
        float4 v3 = p[3 * (size_t)D4];
        float4 v4 = p[4 * (size_t)D4];
        float4 v5 = p[5 * (size_t)D4];
        float4 v6 = p[6 * (size_t)D4];
        float4 v7 = p[7 * (size_t)D4];
        a0 = f4add(a0, v0); a1 = f4add(a1, v1); a2 = f4add(a2, v2); a3 = f4add(a3, v3);
        a4 = f4add(a4, v4); a5 = f4add(a5, v5); a6 = f4add(a6, v6); a7 = f4add(a7, v7);
        p += 8 * (size_t)D4;
    }
    for (; r < hi; ++r) {
        a0 = f4add(a0, p[0]);
        p += D4;
    }
    float4 s = f4add(f4add(f4add(a0, a1), f4add(a2, a3)), f4add(f4add(a4, a5), f4add(a6, a7)));
    float4 vnv = vn4[(size_t)g * D4 + t];
    x4[(size_t)g * D4 + t] = f4fma(s, scale, vnv);
}

// ---------------- bf16 MFMA GEMM: out = [relu](A@W + bias) [+ res] ----------------
// BM=BN=64, BK=32; 4 waves, each wave a 32x32 quadrant as 2x2 16x16x32 frags.
// fp32 tiles staged to LDS via global_load_lds (dbuf); A pre-swizzled on global
// source (c ^= row&7 per 16B chunk) so 16-row ds_read_b128 frag reads are
// conflict-free; fp32->bf16 truncation at fragment read.
template <bool RELU, bool ADD_RES>
__global__ __launch_bounds__(256) void gemm_mfma(const float* __restrict__ A,
        const float* __restrict__ W, const float* __restrict__ bias,
        const float* __restrict__ res, float* __restrict__ out,
        int M, int Nn, int K) {
    __shared__ float lds[2][4096];   // [buf][A 2048 | B 2048] floats = 32 KB
    const int tid = threadIdx.x;
    const int lane = tid & 63;
    const int wid = tid >> 6;
    const int wr = wid >> 1, wc = wid & 1;
    const int lrow = lane & 15;
    const int kg = lane >> 4;
    const int tileM = blockIdx.y * 64;
    const int tileN = blockIdx.x * 64;
    const int nk = K / 32;

    f32x4 acc[2][2] = {};

    #define STAGE(buf, kt) do {                                                   \
        float* Ld = lds[buf];                                                     \
        _Pragma("unroll")                                                         \
        for (int i = 0; i < 2; ++i) {                                             \
            int s = tid + i * 256;                                                \
            int row = s >> 3;                                                     \
            int c = (s & 7) ^ (row & 7);                                          \
            gload16(A + (size_t)(tileM + row) * K + (kt) * 32 + c * 4, Ld + s * 4); \
        }                                                                         \
        _Pragma("unroll")                                                         \
        for (int i = 0; i < 2; ++i) {                                             \
            int s = tid + i * 256;                                                \
            int k = s >> 4, n4 = s & 15;                                          \
            gload16(W + (size_t)((kt) * 32 + k) * Nn + tileN + n4 * 4,            \
                    Ld + 2048 + s * 4);                                           \
        }                                                                         \
    } while (0)

    STAGE(0, 0);
    __syncthreads();

    for (int kt = 0; kt < nk; ++kt) {
        if (kt + 1 < nk) STAGE((kt + 1) & 1, kt + 1);
        const float* As = lds[kt & 1];
        const float* Bs = As + 2048;
        bf16x8 a[2], b[2];
        #pragma unroll
        for (int m = 0; m < 2; ++m) {
            int row = wr * 32 + m * 16 + lrow;
            int c0 = (kg * 2) ^ (row & 7);
            int c1 = (kg * 2 + 1) ^ (row & 7);
            float4 f0 = *(const float4*)(As + (row * 8 + c0) * 4);
            float4 f1 = *(const float4*)(As + (row * 8 + c1) * 4);
            a[m][0] = f2bf(f0.x); a[m][1] = f2bf(f0.y);
            a[m][2] = f2bf(f0.z); a[m][3] = f2bf(f0.w);
            a[m][4] = f2bf(f1.x); a[m][5] = f2bf(f1.y);
            a[m][6] = f2bf(f1.z); a[m][7] = f2bf(f1.w);
        }
        #pragma unroll
        for (int n = 0; n < 2; ++n) {
            int col = wc * 32 + n * 16 + lrow;
            #pragma unroll
            for (int j = 0; j < 8; ++j)
                b[n][j] = f2bf(Bs[(kg * 8 + j) * 64 + col]);
        }
        #pragma unroll
        for (int m = 0; m < 2; ++m)
            #pragma unroll
            for (int n = 0; n < 2; ++n)
                acc[m][n] = __builtin_amdgcn_mfma_f32_16x16x32_bf16(a[m], b[n], acc[m][n], 0, 0, 0);
        __syncthreads();
    }

    // epilogue: C layout col=lane&15, row=(lane>>4)*4+reg
    #pragma unroll
    for (int m = 0; m < 2; ++m) {
        #pragma unroll
        for (int n = 0; n < 2; ++n) {
            int col = tileN + wc * 32 + n * 16 + lrow;
            float bv = bias[col];
            #pragma unroll
            for (int r = 0; r < 4; ++r) {
                int row = tileM + wr * 32 + m * 16 + kg * 4 + r;
                float v = acc[m][n][r] + bv;
                if (RELU) v = fmaxf(v, 0.f);
                if (ADD_RES) v += res[(size_t)row * Nn + col];
                out[(size_t)row * Nn + col] = v;
            }
        }
    }
    #undef STAGE
}

// ---------------- feat_out[node] = feat[node] + y[batch[node]] ----------------
__global__ void node_add_kernel(const float4* __restrict__ feat4, const float4* __restrict__ y4,
                                const int* __restrict__ batch, float4* __restrict__ out4,
                                int N, int D4) {
    int node = blockIdx.x * blockDim.y + threadIdx.y;
    if (node >= N) return;
    int t = threadIdx.x;
    int b = batch[node];
    float4 f = feat4[(size_t)node * D4 + t];
    float4 v = y4[(size_t)b * D4 + t];
    f.x += v.x; f.y += v.y; f.z += v.z; f.w += v.w;
    out4[(size_t)node * D4 + t] = f;
}

extern "C" void kernel_launch(void* const* d_in, const int* in_sizes, int n_in,
                              void* d_out, int out_size, void* d_ws, size_t ws_size,
                              hipStream_t stream) {
    const float* feat  = (const float*)d_in[0];
    const float* vn    = (const float*)d_in[1];
    const float* edge  = (const float*)d_in[2];
    const int*   batch = (const int*)d_in[3];
    const float* fcW   = (const float*)d_in[5];
    const float* fcb   = (const float*)d_in[6];
    const float* pW    = (const float*)d_in[7];
    const float* pb    = (const float*)d_in[8];

    const int D = in_sizes[6];            // 768
    const int N = in_sizes[0] / D;        // 100000
    const int B = in_sizes[1] / D;        // 1024
    const int edge_elems = in_sizes[2];   // B*DE
    const int D4 = D / 4;                 // 192

    float* out_feat = (float*)d_out;
    float* out_vn   = out_feat + (size_t)N * D;
    float* out_edge = out_vn + (size_t)B * D;

    float* x = (float*)d_ws;              // [B, D]
    float* y = x + (size_t)B * D;         // [B, D]

    // 1) pool + vn add -> x
    pool_kernel<<<B, PCOLS, 0, stream>>>((const float4*)feat, (const float4*)vn,
                                         batch, (float4*)x, N, D4);

    // 2) vn_new = vn + relu(x @ fcW + fcb) -> out_vn
    dim3 gdim(D / 64, B / 64);
    gemm_mfma<true, true><<<gdim, THREADS, 0, stream>>>(x, fcW, fcb, vn, out_vn, B, D, D);

    // 3) y = vn_new @ pW + pb
    gemm_mfma<false, false><<<gdim, THREADS, 0, stream>>>(out_vn, pW, pb, nullptr, y, B, D, D);

    // 4) feat_out = feat + y[batch]
    dim3 nblk(192, 2);
    node_add_kernel<<<(N + 1) / 2, nblk, 0, stream>>>((const float4*)feat, (const float4*)y,
                                                      batch, (float4*)out_feat, N, D4);

    // 5) edge passthrough
    hipMemcpyAsync(out_edge, edge, (size_t)edge_elems * sizeof(float),
                   hipMemcpyDeviceToDevice, stream);
}

// Round 5
// 206.467 us; speedup vs baseline: 2.0130x; 1.0774x over previous
//
#include <hip/hip_runtime.h>
#include <cmath>

#define THREADS 256
#define PCOLS 192   // 768 floats / 4 = 192 float4 columns

typedef __attribute__((ext_vector_type(8))) short bf16x8;
typedef __attribute__((ext_vector_type(4))) float f32x4;

__device__ __forceinline__ short f2bf(float f) {
    return (short)(__builtin_bit_cast(unsigned, f) >> 16);
}

typedef const __attribute__((address_space(1))) unsigned int* gas1_t;
typedef __attribute__((address_space(3))) unsigned int* las3_t;
__device__ __forceinline__ void gload16(const float* g, float* l) {
    __builtin_amdgcn_global_load_lds((gas1_t)g, (las3_t)l, 16, 0, 0);
}

__device__ __forceinline__ int lower_bound_i(const int* __restrict__ arr, int n, int val) {
    int lo = 0, hi = n;
    while (lo < hi) {
        int mid = (lo + hi) >> 1;
        if (arr[mid] < val) lo = mid + 1; else hi = mid;
    }
    return lo;
}

__device__ __forceinline__ float4 f4add(float4 a, float4 b) {
    a.x += b.x; a.y += b.y; a.z += b.z; a.w += b.w; return a;
}
__device__ __forceinline__ float4 f4fma(float4 a, float s, float4 b) {
    b.x += a.x * s; b.y += a.y * s; b.z += a.z * s; b.w += a.w * s; return b;
}

// ---------------- pool: x[g] = seg_mean(feat) * log(cnt) + vn[g] ----------------
// Streams feat FORWARD with normal (L3-allocating) loads: at kernel end the L3
// holds the tail of feat, which node_add (backward) consumes first.
__global__ void pool_kernel(const float4* __restrict__ feat4, const float4* __restrict__ vn4,
                            const int* __restrict__ batch, float4* __restrict__ x4,
                            int N, int D4) {
    int g = blockIdx.x;
    __shared__ int s_range[2];
    if (threadIdx.x < 2) s_range[threadIdx.x] = lower_bound_i(batch, N, g + (int)threadIdx.x);
    __syncthreads();
    int lo = s_range[0], hi = s_range[1];
    int cnt = hi - lo;
    float scale = (cnt > 0) ? (logf((float)cnt) / (float)cnt) : 0.f;

    int t = threadIdx.x;
    float4 a0 = {0,0,0,0}, a1 = {0,0,0,0}, a2 = {0,0,0,0}, a3 = {0,0,0,0};
    float4 a4 = {0,0,0,0}, a5 = {0,0,0,0}, a6 = {0,0,0,0}, a7 = {0,0,0,0};

    const float4* __restrict__ p = feat4 + (size_t)lo * D4 + t;
    int r = lo;
    for (; r + 8 <= hi; r += 8) {
        float4 v0 = p[0 * (size_t)D4];
        float4 v1 = p[1 * (size_t)D4];
        float4 v2 = p[2 * (size_t)D4];
        float4 v3 = p[3 * (size_t)D4];
        float4 v4 = p[4 * (size_t)D4];
        float4 v5 = p[5 * (size_t)D4];
        float4 v6 = p[6 * (size_t)D4];
        float4 v7 = p[7 * (size_t)D4];
        a0 = f4add(a0, v0); a1 = f4add(a1, v1); a2 = f4add(a2, v2); a3 = f4add(a3, v3);
        a4 = f4add(a4, v4); a5 = f4add(a5, v5); a6 = f4add(a6, v6); a7 = f4add(a7, v7);
        p += 8 * (size_t)D4;
    }
    for (; r < hi; ++r) {
        a0 = f4add(a0, p[0]);
        p += D4;
    }
    float4 s = f4add(f4add(f4add(a0, a1), f4add(a2, a3)), f4add(f4add(a4, a5), f4add(a6, a7)));
    float4 vnv = vn4[(size_t)g * D4 + t];
    x4[(size_t)g * D4 + t] = f4fma(s, scale, vnv);
}

// ---------------- bf16 MFMA GEMM: out = [relu](A@W + bias) [+ res] ----------------
template <bool RELU, bool ADD_RES>
__global__ __launch_bounds__(256) void gemm_mfma(const float* __restrict__ A,
        const float* __restrict__ W, const float* __restrict__ bias,
        const float* __restrict__ res, float* __restrict__ out,
        int M, int Nn, int K) {
    __shared__ float lds[2][4096];   // [buf][A 2048 | B 2048] floats = 32 KB
    const int tid = threadIdx.x;
    const int lane = tid & 63;
    const int wid = tid >> 6;
    const int wr = wid >> 1, wc = wid & 1;
    const int lrow = lane & 15;
    const int kg = lane >> 4;
    const int tileM = blockIdx.y * 64;
    const int tileN = blockIdx.x * 64;
    const int nk = K / 32;

    f32x4 acc[2][2] = {};

    #define STAGE(buf, kt) do {                                                   \
        float* Ld = lds[buf];                                                     \
        _Pragma("unroll")                                                         \
        for (int i = 0; i < 2; ++i) {                                             \
            int s = tid + i * 256;                                                \
            int row = s >> 3;                                                     \
            int c = (s & 7) ^ (row & 7);                                          \
            gload16(A + (size_t)(tileM + row) * K + (kt) * 32 + c * 4, Ld + s * 4); \
        }                                                                         \
        _Pragma("unroll")                                                         \
        for (int i = 0; i < 2; ++i) {                                             \
            int s = tid + i * 256;                                                \
            int k = s >> 4, n4 = s & 15;                                          \
            gload16(W + (size_t)((kt) * 32 + k) * Nn + tileN + n4 * 4,            \
                    Ld + 2048 + s * 4);                                           \
        }                                                                         \
    } while (0)

    STAGE(0, 0);
    __syncthreads();

    for (int kt = 0; kt < nk; ++kt) {
        if (kt + 1 < nk) STAGE((kt + 1) & 1, kt + 1);
        const float* As = lds[kt & 1];
        const float* Bs = As + 2048;
        bf16x8 a[2], b[2];
        #pragma unroll
        for (int m = 0; m < 2; ++m) {
            int row = wr * 32 + m * 16 + lrow;
            int c0 = (kg * 2) ^ (row & 7);
            int c1 = (kg * 2 + 1) ^ (row & 7);
            float4 f0 = *(const float4*)(As + (row * 8 + c0) * 4);
            float4 f1 = *(const float4*)(As + (row * 8 + c1) * 4);
            a[m][0] = f2bf(f0.x); a[m][1] = f2bf(f0.y);
            a[m][2] = f2bf(f0.z); a[m][3] = f2bf(f0.w);
            a[m][4] = f2bf(f1.x); a[m][5] = f2bf(f1.y);
            a[m][6] = f2bf(f1.z); a[m][7] = f2bf(f1.w);
        }
        #pragma unroll
        for (int n = 0; n < 2; ++n) {
            int col = wc * 32 + n * 16 + lrow;
            #pragma unroll
            for (int j = 0; j < 8; ++j)
                b[n][j] = f2bf(Bs[(kg * 8 + j) * 64 + col]);
        }
        #pragma unroll
        for (int m = 0; m < 2; ++m)
            #pragma unroll
            for (int n = 0; n < 2; ++n)
                acc[m][n] = __builtin_amdgcn_mfma_f32_16x16x32_bf16(a[m], b[n], acc[m][n], 0, 0, 0);
        __syncthreads();
    }

    #pragma unroll
    for (int m = 0; m < 2; ++m) {
        #pragma unroll
        for (int n = 0; n < 2; ++n) {
            int col = tileN + wc * 32 + n * 16 + lrow;
            float bv = bias[col];
            #pragma unroll
            for (int r = 0; r < 4; ++r) {
                int row = tileM + wr * 32 + m * 16 + kg * 4 + r;
                float v = acc[m][n][r] + bv;
                if (RELU) v = fmaxf(v, 0.f);
                if (ADD_RES) v += res[(size_t)row * Nn + col];
                out[(size_t)row * Nn + col] = v;
            }
        }
    }
    #undef STAGE
}

// ---------------- feat_out[node] = feat[node] + y[batch[node]] ----------------
// BACKWARD node order: starts on the feat rows pool read last (L3-resident).
// Non-temporal stores keep the 307 MB output stream from evicting feat in L3.
__global__ void node_add_kernel(const float4* __restrict__ feat4, const float4* __restrict__ y4,
                                const int* __restrict__ batch, float* __restrict__ out,
                                int N, int D4) {
    int node = N - 1 - (int)(blockIdx.x * blockDim.y + threadIdx.y);
    if (node < 0) return;
    int t = threadIdx.x;
    int b = batch[node];
    float4 f = feat4[(size_t)node * D4 + t];
    float4 v = y4[(size_t)b * D4 + t];
    f32x4 r;
    r.x = f.x + v.x; r.y = f.y + v.y; r.z = f.z + v.z; r.w = f.w + v.w;
    f32x4* dst = (f32x4*)(out + ((size_t)node * D4 + t) * 4);
    __builtin_nontemporal_store(r, dst);
}

extern "C" void kernel_launch(void* const* d_in, const int* in_sizes, int n_in,
                              void* d_out, int out_size, void* d_ws, size_t ws_size,
                              hipStream_t stream) {
    const float* feat  = (const float*)d_in[0];
    const float* vn    = (const float*)d_in[1];
    const float* edge  = (const float*)d_in[2];
    const int*   batch = (const int*)d_in[3];
    const float* fcW   = (const float*)d_in[5];
    const float* fcb   = (const float*)d_in[6];
    const float* pW    = (const float*)d_in[7];
    const float* pb    = (const float*)d_in[8];

    const int D = in_sizes[6];            // 768
    const int N = in_sizes[0] / D;        // 100000
    const int B = in_sizes[1] / D;        // 1024
    const int edge_elems = in_sizes[2];   // B*DE
    const int D4 = D / 4;                 // 192

    float* out_feat = (float*)d_out;
    float* out_vn   = out_feat + (size_t)N * D;
    float* out_edge = out_vn + (size_t)B * D;

    float* x = (float*)d_ws;              // [B, D]
    float* y = x + (size_t)B * D;         // [B, D]

    // 1) pool + vn add -> x   (forward stream, fills L3 with feat tail)
    pool_kernel<<<B, PCOLS, 0, stream>>>((const float4*)feat, (const float4*)vn,
                                         batch, (float4*)x, N, D4);

    // 2) vn_new = vn + relu(x @ fcW + fcb) -> out_vn
    dim3 gdim(D / 64, B / 64);
    gemm_mfma<true, true><<<gdim, THREADS, 0, stream>>>(x, fcW, fcb, vn, out_vn, B, D, D);

    // 3) y = vn_new @ pW + pb
    gemm_mfma<false, false><<<gdim, THREADS, 0, stream>>>(out_vn, pW, pb, nullptr, y, B, D, D);

    // 4) feat_out = feat + y[batch]   (backward, nt stores)
    dim3 nblk(192, 2);
    node_add_kernel<<<(N + 1) / 2, nblk, 0, stream>>>((const float4*)feat, (const float4*)y,
                                                      batch, out_feat, N, D4);

    // 5) edge passthrough
    hipMemcpyAsync(out_edge, edge, (size_t)edge_elems * sizeof(float),
                   hipMemcpyDeviceToDevice, stream);
}

// Round 6
// 188.297 us; speedup vs baseline: 2.2072x; 1.0965x over previous
//
#include <hip/hip_runtime.h>
#include <cmath>

#define THREADS 256
#define PCOLS 192   // 768 floats / 4 = 192 float4 columns

typedef __attribute__((ext_vector_type(8))) short bf16x8;
typedef __attribute__((ext_vector_type(4))) float f32x4;

__device__ __forceinline__ short f2bf(float f) {
    return (short)(__builtin_bit_cast(unsigned, f) >> 16);
}

typedef const __attribute__((address_space(1))) unsigned int* gas1_t;
typedef __attribute__((address_space(3))) unsigned int* las3_t;
__device__ __forceinline__ void gload16(const short* g, short* l) {
    __builtin_amdgcn_global_load_lds((gas1_t)g, (las3_t)l, 16, 0, 0);
}

__device__ __forceinline__ int lower_bound_i(const int* __restrict__ arr, int n, int val) {
    int lo = 0, hi = n;
    while (lo < hi) {
        int mid = (lo + hi) >> 1;
        if (arr[mid] < val) lo = mid + 1; else hi = mid;
    }
    return lo;
}

__device__ __forceinline__ float4 f4add(float4 a, float4 b) {
    a.x += b.x; a.y += b.y; a.z += b.z; a.w += b.w; return a;
}
__device__ __forceinline__ float4 f4fma(float4 a, float s, float4 b) {
    b.x += a.x * s; b.y += a.y * s; b.z += a.z * s; b.w += a.w * s; return b;
}

// -------- transpose+convert: dst[n][k] (bf16) = src[k][n] (fp32), square n --------
__global__ void transpose_bf16(const float* __restrict__ src0, short* __restrict__ dst0,
                               const float* __restrict__ src1, short* __restrict__ dst1,
                               int n) {
    const float* src = blockIdx.z ? src1 : src0;
    short* dst = blockIdx.z ? dst1 : dst0;
    __shared__ short tile[32][33];
    int bx = blockIdx.x * 32, by = blockIdx.y * 32;
    int tx = threadIdx.x, ty = threadIdx.y;  // 32 x 8
    #pragma unroll
    for (int i = 0; i < 32; i += 8)
        tile[ty + i][tx] = f2bf(src[(size_t)(by + ty + i) * n + bx + tx]);
    __syncthreads();
    #pragma unroll
    for (int i = 0; i < 32; i += 8)
        dst[(size_t)(bx + ty + i) * n + by + tx] = tile[tx][ty + i];
}

// ---------------- pool: x_bf[g] = bf16( seg_mean(feat)*log(cnt) + vn[g] ) ----------------
// Streams feat FORWARD (L3-allocating); node_add walks backward.
__global__ void pool_kernel(const float4* __restrict__ feat4, const float4* __restrict__ vn4,
                            const int* __restrict__ batch, short* __restrict__ xbf,
                            int N, int D4) {
    int g = blockIdx.x;
    __shared__ int s_range[2];
    if (threadIdx.x < 2) s_range[threadIdx.x] = lower_bound_i(batch, N, g + (int)threadIdx.x);
    __syncthreads();
    int lo = s_range[0], hi = s_range[1];
    int cnt = hi - lo;
    float scale = (cnt > 0) ? (logf((float)cnt) / (float)cnt) : 0.f;

    int t = threadIdx.x;
    float4 a0 = {0,0,0,0}, a1 = {0,0,0,0}, a2 = {0,0,0,0}, a3 = {0,0,0,0};
    float4 a4 = {0,0,0,0}, a5 = {0,0,0,0}, a6 = {0,0,0,0}, a7 = {0,0,0,0};

    const float4* __restrict__ p = feat4 + (size_t)lo * D4 + t;
    int r = lo;
    for (; r + 8 <= hi; r += 8) {
        float4 v0 = p[0 * (size_t)D4];
        float4 v1 = p[1 * (size_t)D4];
        float4 v2 = p[2 * (size_t)D4];
        float4 v3 = p[3 * (size_t)D4];
        float4 v4 = p[4 * (size_t)D4];
        float4 v5 = p[5 * (size_t)D4];
        float4 v6 = p[6 * (size_t)D4];
        float4 v7 = p[7 * (size_t)D4];
        a0 = f4add(a0, v0); a1 = f4add(a1, v1); a2 = f4add(a2, v2); a3 = f4add(a3, v3);
        a4 = f4add(a4, v4); a5 = f4add(a5, v5); a6 = f4add(a6, v6); a7 = f4add(a7, v7);
        p += 8 * (size_t)D4;
    }
    for (; r < hi; ++r) {
        a0 = f4add(a0, p[0]);
        p += D4;
    }
    float4 s = f4add(f4add(f4add(a0, a1), f4add(a2, a3)), f4add(f4add(a4, a5), f4add(a6, a7)));
    float4 vnv = vn4[(size_t)g * D4 + t];
    float4 x = f4fma(s, scale, vnv);
    short4 o;
    o.x = f2bf(x.x); o.y = f2bf(x.y); o.z = f2bf(x.z); o.w = f2bf(x.w);
    *(short4*)(xbf + ((size_t)g * D4 + t) * 4) = o;
}

// ---------------- bf16-native MFMA GEMM ----------------
// out = [relu](A @ Wt^T + bias) [+ res];  A [M][K] bf16, Wt [Nn][K] bf16 (pre-transposed).
// BM=BN=64, BK=32; 4 waves, each a 32x32 quadrant of 2x2 16x16x32 frags.
// LDS tiles [64 rows][4 chunks of 8 bf16], chunk XOR-swizzled via pre-swizzled
// global source (linear LDS dest for global_load_lds). Inner loop: 4 ds_read_b128
// + 4 MFMA per wave per K-step, no conversions.
template <bool RELU, bool ADD_RES, bool WRITE_BF>
__global__ __launch_bounds__(256) void gemm_bf(const short* __restrict__ A,
        const short* __restrict__ Wt, const float* __restrict__ bias,
        const float* __restrict__ res, float* __restrict__ out,
        short* __restrict__ out_bf, int Nn, int K) {
    __shared__ short lds[2][2][64 * 32];   // [buf][A|B][row][k]  4KB each, 16KB total
    const int tid = threadIdx.x;
    const int lane = tid & 63;
    const int wid = tid >> 6;
    const int wr = wid >> 1, wc = wid & 1;
    const int lrow = lane & 15;
    const int kg = lane >> 4;
    const int tileM = blockIdx.y * 64;
    const int tileN = blockIdx.x * 64;
    const int nk = K / 32;

    f32x4 acc[2][2] = {};

    const int srow = tid >> 2;                       // 0..63
    const int sci = (tid & 3) ^ (srow & 3);          // pre-swizzled source chunk

    #define STG(buf, kt) do {                                                    \
        short* La = lds[buf][0];                                                 \
        short* Lb = lds[buf][1];                                                 \
        gload16(A  + (size_t)(tileM + srow) * K + (kt) * 32 + sci * 8, La + tid * 8); \
        gload16(Wt + (size_t)(tileN + srow) * K + (kt) * 32 + sci * 8, Lb + tid * 8); \
    } while (0)

    STG(0, 0);
    __syncthreads();

    for (int kt = 0; kt < nk; ++kt) {
        if (kt + 1 < nk) STG((kt + 1) & 1, kt + 1);
        const short* La = lds[kt & 1][0];
        const short* Lb = lds[kt & 1][1];
        bf16x8 a[2], b[2];
        #pragma unroll
        for (int m = 0; m < 2; ++m) {
            int row = wr * 32 + m * 16 + lrow;
            a[m] = *(const bf16x8*)(La + row * 32 + ((kg ^ (row & 3)) * 8));
        }
        #pragma unroll
        for (int n = 0; n < 2; ++n) {
            int col = wc * 32 + n * 16 + lrow;
            b[n] = *(const bf16x8*)(Lb + col * 32 + ((kg ^ (col & 3)) * 8));
        }
        #pragma unroll
        for (int m = 0; m < 2; ++m)
            #pragma unroll
            for (int n = 0; n < 2; ++n)
                acc[m][n] = __builtin_amdgcn_mfma_f32_16x16x32_bf16(a[m], b[n], acc[m][n], 0, 0, 0);
        __syncthreads();
    }

    // epilogue: C layout col=lane&15, row=(lane>>4)*4+reg
    #pragma unroll
    for (int m = 0; m < 2; ++m) {
        #pragma unroll
        for (int n = 0; n < 2; ++n) {
            int col = tileN + wc * 32 + n * 16 + lrow;
            float bv = bias[col];
            #pragma unroll
            for (int r = 0; r < 4; ++r) {
                int row = tileM + wr * 32 + m * 16 + kg * 4 + r;
                float v = acc[m][n][r] + bv;
                if (RELU) v = fmaxf(v, 0.f);
                if (ADD_RES) v += res[(size_t)row * Nn + col];
                out[(size_t)row * Nn + col] = v;
                if (WRITE_BF) out_bf[(size_t)row * Nn + col] = f2bf(v);
            }
        }
    }
    #undef STG
}

// ---------------- feat_out[node] = feat[node] + y[batch[node]] ----------------
// BACKWARD order (consumes pool's L3-resident tail first); nt stores keep the
// 307 MB output stream from evicting feat in L3.
__global__ void node_add_kernel(const float4* __restrict__ feat4, const float4* __restrict__ y4,
                                const int* __restrict__ batch, float* __restrict__ out,
                                int N, int D4) {
    int node = N - 1 - (int)(blockIdx.x * blockDim.y + threadIdx.y);
    if (node < 0) return;
    int t = threadIdx.x;
    int b = batch[node];
    float4 f = feat4[(size_t)node * D4 + t];
    float4 v = y4[(size_t)b * D4 + t];
    f32x4 r;
    r.x = f.x + v.x; r.y = f.y + v.y; r.z = f.z + v.z; r.w = f.w + v.w;
    f32x4* dst = (f32x4*)(out + ((size_t)node * D4 + t) * 4);
    __builtin_nontemporal_store(r, dst);
}

extern "C" void kernel_launch(void* const* d_in, const int* in_sizes, int n_in,
                              void* d_out, int out_size, void* d_ws, size_t ws_size,
                              hipStream_t stream) {
    const float* feat  = (const float*)d_in[0];
    const float* vn    = (const float*)d_in[1];
    const float* edge  = (const float*)d_in[2];
    const int*   batch = (const int*)d_in[3];
    const float* fcW   = (const float*)d_in[5];
    const float* fcb   = (const float*)d_in[6];
    const float* pW    = (const float*)d_in[7];
    const float* pb    = (const float*)d_in[8];

    const int D = in_sizes[6];            // 768
    const int N = in_sizes[0] / D;        // 100000
    const int B = in_sizes[1] / D;        // 1024
    const int edge_elems = in_sizes[2];   // B*DE
    const int D4 = D / 4;                 // 192

    float* out_feat = (float*)d_out;
    float* out_vn   = out_feat + (size_t)N * D;
    float* out_edge = out_vn + (size_t)B * D;

    // workspace layout (bytes)
    char* ws = (char*)d_ws;
    short* xbf  = (short*)ws;                              // [B][D] bf16
    short* x2bf = (short*)(ws + (size_t)B * D * 2);        // [B][D] bf16
    short* fcWt = (short*)(ws + (size_t)B * D * 4);        // [D][D] bf16 (transposed)
    short* pWt  = (short*)(ws + (size_t)B * D * 4 + (size_t)D * D * 2);
    float* y    = (float*)(ws + (size_t)B * D * 4 + (size_t)D * D * 4);  // [B][D] f32

    // 0) weights -> transposed bf16 (once per call)
    dim3 tb(32, 8);
    dim3 tg(D / 32, D / 32, 2);
    transpose_bf16<<<tg, tb, 0, stream>>>(fcW, fcWt, pW, pWt, D);

    // 1) pool + vn add -> x (bf16)
    pool_kernel<<<B, PCOLS, 0, stream>>>((const float4*)feat, (const float4*)vn,
                                         batch, xbf, N, D4);

    // 2) vn_new = vn + relu(x @ fcW + fcb) -> out_vn (f32) + x2 (bf16)
    dim3 gdim(D / 64, B / 64);
    gemm_bf<true, true, true><<<gdim, THREADS, 0, stream>>>(xbf, fcWt, fcb, vn,
                                                            out_vn, x2bf, D, D);

    // 3) y = vn_new @ pW + pb
    gemm_bf<false, false, false><<<gdim, THREADS, 0, stream>>>(x2bf, pWt, pb, nullptr,
                                                               y, nullptr, D, D);

    // 4) feat_out = feat + y[batch]   (backward, nt stores)
    dim3 nblk(192, 2);
    node_add_kernel<<<(N + 1) / 2, nblk, 0, stream>>>((const float4*)feat, (const float4*)y,
                                                      batch, out_feat, N, D4);

    // 5) edge passthrough
    hipMemcpyAsync(out_edge, edge, (size_t)edge_elems * sizeof(float),
                   hipMemcpyDeviceToDevice, stream);
}

// Round 7
// 182.890 us; speedup vs baseline: 2.2725x; 1.0296x over previous
//
#include <hip/hip_runtime.h>
#include <cmath>

#define THREADS 256
#define PCOLS 192       // 768 floats / 4 = 192 float4 columns
#define T_RESIDENT 72000  // feat rows < T pinned in L3 (221 MB of 256 MB)

typedef __attribute__((ext_vector_type(8))) short bf16x8;
typedef __attribute__((ext_vector_type(4))) float f32x4;

__device__ __forceinline__ short f2bf(float f) {
    return (short)(__builtin_bit_cast(unsigned, f) >> 16);
}

typedef const __attribute__((address_space(1))) unsigned int* gas1_t;
typedef __attribute__((address_space(3))) unsigned int* las3_t;
__device__ __forceinline__ void gload16(const short* g, short* l) {
    __builtin_amdgcn_global_load_lds((gas1_t)g, (las3_t)l, 16, 0, 0);
}

__device__ __forceinline__ int lower_bound_i(const int* __restrict__ arr, int n, int val) {
    int lo = 0, hi = n;
    while (lo < hi) {
        int mid = (lo + hi) >> 1;
        if (arr[mid] < val) lo = mid + 1; else hi = mid;
    }
    return lo;
}

__device__ __forceinline__ float4 f4add(float4 a, float4 b) {
    a.x += b.x; a.y += b.y; a.z += b.z; a.w += b.w; return a;
}
__device__ __forceinline__ float4 f4fma(float4 a, float s, float4 b) {
    b.x += a.x * s; b.y += a.y * s; b.z += a.z * s; b.w += a.w * s; return b;
}

template <bool NT>
__device__ __forceinline__ float4 ldf4(const float4* p) {
    if constexpr (NT) {
        f32x4 v = __builtin_nontemporal_load((const f32x4*)p);
        float4 r; r.x = v.x; r.y = v.y; r.z = v.z; r.w = v.w; return r;
    } else {
        return *p;
    }
}

// -------- transpose+convert: dst[n][k] (bf16) = src[k][n] (fp32), square n --------
__global__ void transpose_bf16(const float* __restrict__ src0, short* __restrict__ dst0,
                               const float* __restrict__ src1, short* __restrict__ dst1,
                               int n) {
    const float* src = blockIdx.z ? src1 : src0;
    short* dst = blockIdx.z ? dst1 : dst0;
    __shared__ short tile[32][33];
    int bx = blockIdx.x * 32, by = blockIdx.y * 32;
    int tx = threadIdx.x, ty = threadIdx.y;  // 32 x 8
    #pragma unroll
    for (int i = 0; i < 32; i += 8)
        tile[ty + i][tx] = f2bf(src[(size_t)(by + ty + i) * n + bx + tx]);
    __syncthreads();
    #pragma unroll
    for (int i = 0; i < 32; i += 8)
        dst[(size_t)(bx + ty + i) * n + by + tx] = tile[tx][ty + i];
}

// ---------------- pool: x_bf[g] = bf16( seg_mean(feat)*log(cnt) + vn[g] ) ----------------
// Rows < Tres: normal loads (allocate in L3, stay resident). Rows >= Tres: nt
// loads (stream, don't evict the resident set).
template <bool NT>
__device__ __forceinline__ void accum8(const float4* __restrict__ base, int a, int b, int D4, int t,
                                       float4& a0, float4& a1, float4& a2, float4& a3,
                                       float4& a4, float4& a5, float4& a6, float4& a7) {
    const float4* __restrict__ p = base + (size_t)a * D4 + t;
    int r = a;
    for (; r + 8 <= b; r += 8) {
        float4 v0 = ldf4<NT>(p + 0 * (size_t)D4);
        float4 v1 = ldf4<NT>(p + 1 * (size_t)D4);
        float4 v2 = ldf4<NT>(p + 2 * (size_t)D4);
        float4 v3 = ldf4<NT>(p + 3 * (size_t)D4);
        float4 v4 = ldf4<NT>(p + 4 * (size_t)D4);
        float4 v5 = ldf4<NT>(p + 5 * (size_t)D4);
        float4 v6 = ldf4<NT>(p + 6 * (size_t)D4);
        float4 v7 = ldf4<NT>(p + 7 * (size_t)D4);
        a0 = f4add(a0, v0); a1 = f4add(a1, v1); a2 = f4add(a2, v2); a3 = f4add(a3, v3);
        a4 = f4add(a4, v4); a5 = f4add(a5, v5); a6 = f4add(a6, v6); a7 = f4add(a7, v7);
        p += 8 * (size_t)D4;
    }
    for (; r < b; ++r) {
        a0 = f4add(a0, ldf4<NT>(p));
        p += D4;
    }
}

__global__ void pool_kernel(const float4* __restrict__ feat4, const float4* __restrict__ vn4,
                            const int* __restrict__ batch, short* __restrict__ xbf,
                            int N, int D4, int Tres) {
    int g = blockIdx.x;
    __shared__ int s_range[2];
    if (threadIdx.x < 2) s_range[threadIdx.x] = lower_bound_i(batch, N, g + (int)threadIdx.x);
    __syncthreads();
    int lo = s_range[0], hi = s_range[1];
    int cnt = hi - lo;
    float scale = (cnt > 0) ? (logf((float)cnt) / (float)cnt) : 0.f;

    int t = threadIdx.x;
    float4 a0 = {0,0,0,0}, a1 = {0,0,0,0}, a2 = {0,0,0,0}, a3 = {0,0,0,0};
    float4 a4 = {0,0,0,0}, a5 = {0,0,0,0}, a6 = {0,0,0,0}, a7 = {0,0,0,0};

    int m = hi < Tres ? hi : (lo > Tres ? lo : Tres);  // clamp(Tres, lo, hi)
    accum8<false>(feat4, lo, m, D4, t, a0, a1, a2, a3, a4, a5, a6, a7);
    accum8<true >(feat4, m, hi, D4, t, a0, a1, a2, a3, a4, a5, a6, a7);

    float4 s = f4add(f4add(f4add(a0, a1), f4add(a2, a3)), f4add(f4add(a4, a5), f4add(a6, a7)));
    float4 vnv = vn4[(size_t)g * D4 + t];
    float4 x = f4fma(s, scale, vnv);
    short4 o;
    o.x = f2bf(x.x); o.y = f2bf(x.y); o.z = f2bf(x.z); o.w = f2bf(x.w);
    *(short4*)(xbf + ((size_t)g * D4 + t) * 4) = o;
}

// ---------------- bf16-native MFMA GEMM ----------------
template <bool RELU, bool ADD_RES, bool WRITE_BF>
__global__ __launch_bounds__(256) void gemm_bf(const short* __restrict__ A,
        const short* __restrict__ Wt, const float* __restrict__ bias,
        const float* __restrict__ res, float* __restrict__ out,
        short* __restrict__ out_bf, int Nn, int K) {
    __shared__ short lds[2][2][64 * 32];
    const int tid = threadIdx.x;
    const int lane = tid & 63;
    const int wid = tid >> 6;
    const int wr = wid >> 1, wc = wid & 1;
    const int lrow = lane & 15;
    const int kg = lane >> 4;
    const int tileM = blockIdx.y * 64;
    const int tileN = blockIdx.x * 64;
    const int nk = K / 32;

    f32x4 acc[2][2] = {};

    const int srow = tid >> 2;
    const int sci = (tid & 3) ^ (srow & 3);

    #define STG(buf, kt) do {                                                    \
        short* La = lds[buf][0];                                                 \
        short* Lb = lds[buf][1];                                                 \
        gload16(A  + (size_t)(tileM + srow) * K + (kt) * 32 + sci * 8, La + tid * 8); \
        gload16(Wt + (size_t)(tileN + srow) * K + (kt) * 32 + sci * 8, Lb + tid * 8); \
    } while (0)

    STG(0, 0);
    __syncthreads();

    for (int kt = 0; kt < nk; ++kt) {
        if (kt + 1 < nk) STG((kt + 1) & 1, kt + 1);
        const short* La = lds[kt & 1][0];
        const short* Lb = lds[kt & 1][1];
        bf16x8 a[2], b[2];
        #pragma unroll
        for (int m = 0; m < 2; ++m) {
            int row = wr * 32 + m * 16 + lrow;
            a[m] = *(const bf16x8*)(La + row * 32 + ((kg ^ (row & 3)) * 8));
        }
        #pragma unroll
        for (int n = 0; n < 2; ++n) {
            int col = wc * 32 + n * 16 + lrow;
            b[n] = *(const bf16x8*)(Lb + col * 32 + ((kg ^ (col & 3)) * 8));
        }
        #pragma unroll
        for (int m = 0; m < 2; ++m)
            #pragma unroll
            for (int n = 0; n < 2; ++n)
                acc[m][n] = __builtin_amdgcn_mfma_f32_16x16x32_bf16(a[m], b[n], acc[m][n], 0, 0, 0);
        __syncthreads();
    }

    #pragma unroll
    for (int m = 0; m < 2; ++m) {
        #pragma unroll
        for (int n = 0; n < 2; ++n) {
            int col = tileN + wc * 32 + n * 16 + lrow;
            float bv = bias[col];
            #pragma unroll
            for (int r = 0; r < 4; ++r) {
                int row = tileM + wr * 32 + m * 16 + kg * 4 + r;
                float v = acc[m][n][r] + bv;
                if (RELU) v = fmaxf(v, 0.f);
                if (ADD_RES) v += res[(size_t)row * Nn + col];
                out[(size_t)row * Nn + col] = v;
                if (WRITE_BF) out_bf[(size_t)row * Nn + col] = f2bf(v);
            }
        }
    }
    #undef STG
}

// ---------------- feat_out[node] = feat[node] + y[batch[node]] ----------------
// Rows < Tres read normally (keep resident), rows >= Tres read nt (stream).
// Output always nt-stored (never pollutes L3).
__global__ void node_add_kernel(const float4* __restrict__ feat4, const float4* __restrict__ y4,
                                const int* __restrict__ batch, float* __restrict__ out,
                                int N, int D4, int Tres) {
    int node = (int)(blockIdx.x * blockDim.y + threadIdx.y);
    if (node >= N) return;
    int t = threadIdx.x;
    int b = batch[node];
    size_t idx = (size_t)node * D4 + t;
    float4 f = (node < Tres) ? feat4[idx] : ldf4<true>(&feat4[idx]);
    float4 v = y4[(size_t)b * D4 + t];
    f32x4 r;
    r.x = f.x + v.x; r.y = f.y + v.y; r.z = f.z + v.z; r.w = f.w + v.w;
    f32x4* dst = (f32x4*)(out + idx * 4);
    __builtin_nontemporal_store(r, dst);
}

extern "C" void kernel_launch(void* const* d_in, const int* in_sizes, int n_in,
                              void* d_out, int out_size, void* d_ws, size_t ws_size,
                              hipStream_t stream) {
    const float* feat  = (const float*)d_in[0];
    const float* vn    = (const float*)d_in[1];
    const float* edge  = (const float*)d_in[2];
    const int*   batch = (const int*)d_in[3];
    const float* fcW   = (const float*)d_in[5];
    const float* fcb   = (const float*)d_in[6];
    const float* pW    = (const float*)d_in[7];
    const float* pb    = (const float*)d_in[8];

    const int D = in_sizes[6];            // 768
    const int N = in_sizes[0] / D;        // 100000
    const int B = in_sizes[1] / D;        // 1024
    const int edge_elems = in_sizes[2];   // B*DE
    const int D4 = D / 4;                 // 192

    float* out_feat = (float*)d_out;
    float* out_vn   = out_feat + (size_t)N * D;
    float* out_edge = out_vn + (size_t)B * D;

    char* ws = (char*)d_ws;
    short* xbf  = (short*)ws;                              // [B][D] bf16
    short* x2bf = (short*)(ws + (size_t)B * D * 2);        // [B][D] bf16
    short* fcWt = (short*)(ws + (size_t)B * D * 4);        // [D][D] bf16 (transposed)
    short* pWt  = (short*)(ws + (size_t)B * D * 4 + (size_t)D * D * 2);
    float* y    = (float*)(ws + (size_t)B * D * 4 + (size_t)D * D * 4);  // [B][D] f32

    // 0) weights -> transposed bf16
    dim3 tb(32, 8);
    dim3 tg(D / 32, D / 32, 2);
    transpose_bf16<<<tg, tb, 0, stream>>>(fcW, fcWt, pW, pWt, D);

    // 1) pool + vn add -> x (bf16)
    pool_kernel<<<B, PCOLS, 0, stream>>>((const float4*)feat, (const float4*)vn,
                                         batch, xbf, N, D4, T_RESIDENT);

    // 2) vn_new = vn + relu(x @ fcW + fcb) -> out_vn (f32) + x2 (bf16)
    dim3 gdim(D / 64, B / 64);
    gemm_bf<true, true, true><<<gdim, THREADS, 0, stream>>>(xbf, fcWt, fcb, vn,
                                                            out_vn, x2bf, D, D);

    // 3) y = vn_new @ pW + pb
    gemm_bf<false, false, false><<<gdim, THREADS, 0, stream>>>(x2bf, pWt, pb, nullptr,
                                                               y, nullptr, D, D);

    // 4) feat_out = feat + y[batch]
    dim3 nblk(192, 2);
    node_add_kernel<<<(N + 1) / 2, nblk, 0, stream>>>((const float4*)feat, (const float4*)y,
                                                      batch, out_feat, N, D4, T_RESIDENT);

    // 5) edge passthrough
    hipMemcpyAsync(out_edge, edge, (size_t)edge_elems * sizeof(float),
                   hipMemcpyDeviceToDevice, stream);
}